// Round 4
// baseline (13777.074 us; speedup 1.0000x reference)
//
#include <hip/hip_runtime.h>
#include <cmath>
#include <complex>

#define MULT 64
#define NODE_DIM 576   // 64*(1+3+5)
#define TE 8           // edges per block in edge kernel

// ---------------------------------------------------------------------------
// Host-side Wigner/CG computation (exact replica of the reference math,
// done in double precision, alpha folded in). ~µs of host work per call,
// deterministic.
// ---------------------------------------------------------------------------
typedef std::complex<double> cd;

static double factd(int n){ double r=1; for(int i=2;i<=n;i++) r*=(double)i; return r; }

static double su2_cg(int j1,int j2,int j3,int m1,int m2,int m3){
  if(m1+m2!=m3) return 0.0;
  double pref = (2*j3+1)*factd(j1+j2-j3)*factd(j1-j2+j3)*factd(-j1+j2+j3)/factd(j1+j2+j3+1)
              * factd(j1+m1)*factd(j1-m1)*factd(j2+m2)*factd(j2-m2)*factd(j3+m3)*factd(j3-m3);
  pref = std::sqrt(pref);
  double s=0;
  for(int k=0;k<=j1+j2+j3;k++){
    int d0=k, d1=j1+j2-j3-k, d2=j1-m1-k, d3=j2+m2-k, d4=j3-j2+m1+k, d5=j3-j1-m2+k;
    if(d0<0||d1<0||d2<0||d3<0||d4<0||d5<0) continue;
    double denom = factd(d0)*factd(d1)*factd(d2)*factd(d3)*factd(d4)*factd(d5);
    s += ((k&1)?-1.0:1.0)/denom;
  }
  return pref*s;
}

static void make_q(int l, cd q[5][5]){
  for(int i=0;i<5;i++)for(int j=0;j<5;j++) q[i][j]=cd(0,0);
  double s = 1.0/std::sqrt(2.0);
  for(int m=-l;m<0;m++){
    q[l+m][l-m] = cd(s,0);     // col l+|m|
    q[l+m][l+m] = cd(0,-s);    // col l-|m|
  }
  q[l][l]=cd(1,0);
  for(int m=1;m<=l;m++){
    double sg = (m&1)?-1.0:1.0;
    q[l+m][l+m]=cd(sg*s,0);
    q[l+m][l-m]=cd(0,sg*s);
  }
  cd ph = (l==0)?cd(1,0) : ((l==1)?cd(0,-1) : cd(-1,0)); // (-i)^l
  for(int i=0;i<2*l+1;i++)for(int j=0;j<2*l+1;j++) q[i][j]*=ph;
}

static void real_cg(int l1,int l2,int l3, double* out){
  int d1=2*l1+1,d2=2*l2+1,d3=2*l3+1;
  double cg[125];
  for(int a=0;a<d1;a++)for(int b=0;b<d2;b++)for(int c=0;c<d3;c++)
    cg[(a*d2+b)*d3+c] = su2_cg(l1,l2,l3,a-l1,b-l2,c-l3);
  cd q1[5][5],q2[5][5],q3[5][5];
  make_q(l1,q1); make_q(l2,q2); make_q(l3,q3);
  cd C[125];
  for(int t=0;t<d1*d2*d3;t++) C[t]=cd(0,0);
  for(int i=0;i<d1;i++)for(int k=0;k<d2;k++)for(int n=0;n<d3;n++){
    double v = cg[(i*d2+k)*d3+n];
    if(v==0.0) continue;
    for(int j=0;j<d1;j++){
      cd a = q1[i][j]*v;
      if(a.real()==0.0 && a.imag()==0.0) continue;
      for(int l=0;l<d2;l++){
        cd b = a*q2[k][l];
        for(int m=0;m<d3;m++) C[(j*d2+l)*d3+m] += b*std::conj(q3[n][m]);
      }
    }
  }
  double sre=0,sim=0;
  for(int t=0;t<d1*d2*d3;t++){ sre+=std::fabs(C[t].real()); sim+=std::fabs(C[t].imag()); }
  bool use_re = (sre>=sim);
  double nrm=0;
  for(int t=0;t<d1*d2*d3;t++){ double x=use_re?C[t].real():C[t].imag(); nrm+=x*x; }
  nrm=std::sqrt(nrm);
  for(int t=0;t<d1*d2*d3;t++){ double x=use_re?C[t].real():C[t].imag(); out[t]=x/nrm; }
}

// Flat CG pack with per-instruction offsets (sizes: 1,9,25,9,9,45,45,25,45,25,125)
struct CGPack { float v[363]; };

// ---------------------------------------------------------------------------
// Device kernels
// ---------------------------------------------------------------------------
__device__ __forceinline__ float silu_f(float x){ return x/(1.f+expf(-x)); }
__host__ __device__ constexpr int LOFF(int l){ return l==0?0:(l==1?1:4); }

template<int DI,int DJ,int DK>
__device__ __forceinline__ void tp_add(const float* __restrict__ C, const float* xi,
                                       const float* sh, float wn, float* mk){
  float tmp[DK];
#pragma unroll
  for(int c=0;c<DK;c++) tmp[c]=0.f;
#pragma unroll
  for(int a=0;a<DI;a++){
#pragma unroll
    for(int b=0;b<DJ;b++){
      float p = xi[a]*sh[b];
#pragma unroll
      for(int c=0;c<DK;c++) tmp[c] = fmaf(C[(a*DJ+b)*DK+c], p, tmp[c]);
    }
  }
#pragma unroll
  for(int c=0;c<DK;c++) mk[c] = fmaf(wn, tmp[c], mk[c]);
}

__global__ __launch_bounds__(512,1) void emp_edge_kernel(
  const float* __restrict__ nf, const int* __restrict__ src_idx, const int* __restrict__ dst_idx,
  const float* __restrict__ evec, const float* __restrict__ w0, const float* __restrict__ w1,
  const float* __restrict__ w2, float* __restrict__ aggr, int E, CGPack cgp)
{
  __shared__ float s_h0[TE][64];
  __shared__ float s_h1[TE][64];
  __shared__ float s_sh[TE][9];
  __shared__ int   s_sd[TE][2];
  __shared__ float s_tile[64][64];   // fc_w2 column tile for one instruction

  const int t  = threadIdx.x;
  const int u  = t & 63;             // mul channel
  const int es = t >> 6;             // edge slot within block (one wave per edge)
  const int e  = blockIdx.x*TE + es;
  const bool valid = (e < E);

  // --- phase A: dist, SH, first MLP layer -------------------------------
  float dist = 0.f;
  if(valid){
    float ex = evec[e*3+0], ey = evec[e*3+1], ez = evec[e*3+2];
    dist = sqrtf(ex*ex+ey*ey+ez*ez);
    if(u==0){
      float inv = 1.f/fmaxf(dist,1e-9f);
      float x=ex*inv, y=ey*inv, z=ez*inv;
      const float s3=1.7320508075688772f, s5=2.2360679774997896f;
      s_sh[es][0]=1.f;
      s_sh[es][1]=s3*y; s_sh[es][2]=s3*z; s_sh[es][3]=s3*x;
      s_sh[es][4]=s5*s3*x*y; s_sh[es][5]=s5*s3*y*z; s_sh[es][6]=s5*(1.5f*z*z-0.5f);
      s_sh[es][7]=s5*s3*x*z; s_sh[es][8]=s5*0.5f*s3*(x*x-y*y);
      s_sd[es][0]=src_idx[e]; s_sd[es][1]=dst_idx[e];
    }
  }
  s_h0[es][u] = silu_f(dist * w0[u]);
  __syncthreads();

  // --- phase B: second MLP layer ----------------------------------------
  float acc = 0.f;
#pragma unroll
  for(int k=0;k<64;k++) acc = fmaf(s_h0[es][k], w1[k*64+u], acc);
  s_h1[es][u] = silu_f(acc*0.125f);
  // (published by the __syncthreads() at the top of the first TP step)

  // --- per-thread state: x fragments, sh copy, msg accumulators ---------
  float xa[9], shv[9], mg[9];
#pragma unroll
  for(int i=0;i<9;i++) mg[i]=0.f;
  int srcn=0, dstn=0;
  if(valid){ srcn = s_sd[es][0]; dstn = s_sd[es][1]; }
#pragma unroll
  for(int i=0;i<9;i++) shv[i] = valid ? s_sh[es][i] : 0.f;
  if(valid){
    const float* row = nf + (size_t)srcn*NODE_DIM;
    xa[0] = row[u];
#pragma unroll
    for(int a=0;a<3;a++) xa[1+a]=row[64+u*3+a];
#pragma unroll
    for(int a=0;a<5;a++) xa[4+a]=row[256+u*5+a];
  } else {
#pragma unroll
    for(int i=0;i<9;i++) xa[i]=0.f;
  }

  // --- phase C: 11 TP instructions, LDS-staged fc_w2 tile each ----------
#define TP_INST(N, LI, LJ, LK, OFF)                                         \
  {                                                                          \
    __syncthreads();                                                         \
    _Pragma("unroll")                                                        \
    for(int r=0;r<8;r++){ int k=es+r*8; s_tile[k][u] = w2[k*704 + (N)*64 + u]; } \
    __syncthreads();                                                         \
    float wn=0.f;                                                            \
    _Pragma("unroll")                                                        \
    for(int k=0;k<64;k++) wn = fmaf(s_h1[es][k], s_tile[k][u], wn);          \
    wn *= 0.125f;                                                            \
    tp_add<2*(LI)+1,2*(LJ)+1,2*(LK)+1>(cgp.v+(OFF), xa+LOFF(LI),             \
                                       shv+LOFF(LJ), wn, mg+LOFF(LK));       \
  }

  TP_INST(0,0,0,0,0)
  TP_INST(1,0,1,1,1)
  TP_INST(2,0,2,2,10)
  TP_INST(3,1,0,1,35)
  TP_INST(4,1,1,0,44)
  TP_INST(5,1,1,2,53)
  TP_INST(6,1,2,1,98)
  TP_INST(7,2,0,2,143)
  TP_INST(8,2,1,1,168)
  TP_INST(9,2,2,0,213)
  TP_INST(10,2,2,2,238)
#undef TP_INST

  // --- phase D: atomic scatter into aggr[dst] ---------------------------
  if(valid){
    float* arow = aggr + (size_t)dstn*NODE_DIM;
    atomicAdd(&arow[u], mg[0]);
#pragma unroll
    for(int c=0;c<3;c++) atomicAdd(&arow[64+u*3+c], mg[1+c]);
#pragma unroll
    for(int c=0;c<5;c++) atomicAdd(&arow[256+u*5+c], mg[4+c]);
  }
}

// Per-node: out_row = blockdiag-linear(aggr_row)/8 + node_feat_row, in place.
__global__ __launch_bounds__(64) void emp_node_kernel(
  const float* __restrict__ nf, const float* __restrict__ lw,
  float* __restrict__ out, int N)
{
  __shared__ float s_a[NODE_DIM];
  const int n = blockIdx.x;
  const int v = threadIdx.x;   // output channel
  float* orow = out + (size_t)n*NODE_DIM;
#pragma unroll
  for(int r=0;r<9;r++) s_a[r*64+v] = orow[r*64+v];
  __syncthreads();

  float o0=0.f, o1[3]={0.f,0.f,0.f}, o2[5]={0.f,0.f,0.f,0.f,0.f};
#pragma unroll 8
  for(int uu=0;uu<64;uu++){
    float wv0 = lw[uu*64+v];
    o0 = fmaf(s_a[uu], wv0, o0);
    float wv1 = lw[4096+uu*64+v];
#pragma unroll
    for(int d=0;d<3;d++) o1[d]=fmaf(s_a[64+uu*3+d],wv1,o1[d]);
    float wv2 = lw[8192+uu*64+v];
#pragma unroll
    for(int d=0;d<5;d++) o2[d]=fmaf(s_a[256+uu*5+d],wv2,o2[d]);
  }
  const float* nrow = nf + (size_t)n*NODE_DIM;
  orow[v] = fmaf(o0,0.125f,nrow[v]);
#pragma unroll
  for(int d=0;d<3;d++) orow[64+v*3+d]=fmaf(o1[d],0.125f,nrow[64+v*3+d]);
#pragma unroll
  for(int d=0;d<5;d++) orow[256+v*5+d]=fmaf(o2[d],0.125f,nrow[256+v*5+d]);
}

// ---------------------------------------------------------------------------
extern "C" void kernel_launch(void* const* d_in, const int* in_sizes, int n_in,
                              void* d_out, int out_size, void* d_ws, size_t ws_size,
                              hipStream_t stream)
{
  const float* nf   = (const float*)d_in[0];
  const int*   eidx = (const int*)  d_in[1];
  const float* evec = (const float*)d_in[2];
  const float* w0   = (const float*)d_in[3];
  const float* w1   = (const float*)d_in[4];
  const float* w2   = (const float*)d_in[5];
  const float* lw   = (const float*)d_in[6];
  const int E = in_sizes[1]/2;
  const int N = in_sizes[0]/NODE_DIM;

  // Build CG pack (with alpha = sqrt((2*lk+1)/n_paths[lk]) folded in).
  CGPack cgp;
  {
    const int II[11]={0,0,0,1,1,1,1,2,2,2,2};
    const int JJ[11]={0,1,2,0,1,1,2,0,1,2,2};
    const int KK[11]={0,1,2,1,0,2,1,2,1,0,2};
    const int OFF[11]={0,1,10,35,44,53,98,143,168,213,238};
    const double npaths[3]={3.0,4.0,4.0};
    double tmp[125];
    for(int n=0;n<11;n++){
      int li=II[n], lj=JJ[n], lk=KK[n];
      real_cg(li,lj,lk,tmp);
      double alpha = std::sqrt((2.0*lk+1.0)/npaths[lk]);
      int sz=(2*li+1)*(2*lj+1)*(2*lk+1);
      for(int q=0;q<sz;q++) cgp.v[OFF[n]+q]=(float)(tmp[q]*alpha);
    }
  }

  float* aggr = (float*)d_out;  // use d_out as the aggregation buffer
  hipMemsetAsync(d_out, 0, (size_t)N*NODE_DIM*sizeof(float), stream);

  const int nblk = (E+TE-1)/TE;
  hipLaunchKernelGGL(emp_edge_kernel, dim3(nblk), dim3(512), 0, stream,
                     nf, eidx, eidx+E, evec, w0, w1, w2, aggr, E, cgp);
  hipLaunchKernelGGL(emp_node_kernel, dim3(N), dim3(64), 0, stream,
                     nf, lw, (float*)d_out, N);
}

// Round 5
// 1226.191 us; speedup vs baseline: 11.2357x; 11.2357x over previous
//
#include <hip/hip_runtime.h>
#include <cmath>
#include <complex>

#define MULT 64
#define NODE_DIM 576   // 64*(1+3+5)
#define TE 8           // edges per block in pre/edge kernels

// ---------------------------------------------------------------------------
// Host-side Wigner/CG computation (exact replica of the reference math,
// double precision, alpha folded in). Deterministic, ~µs per call.
// ---------------------------------------------------------------------------
typedef std::complex<double> cd;

static double factd(int n){ double r=1; for(int i=2;i<=n;i++) r*=(double)i; return r; }

static double su2_cg(int j1,int j2,int j3,int m1,int m2,int m3){
  if(m1+m2!=m3) return 0.0;
  double pref = (2*j3+1)*factd(j1+j2-j3)*factd(j1-j2+j3)*factd(-j1+j2+j3)/factd(j1+j2+j3+1)
              * factd(j1+m1)*factd(j1-m1)*factd(j2+m2)*factd(j2-m2)*factd(j3+m3)*factd(j3-m3);
  pref = std::sqrt(pref);
  double s=0;
  for(int k=0;k<=j1+j2+j3;k++){
    int d0=k, d1=j1+j2-j3-k, d2=j1-m1-k, d3=j2+m2-k, d4=j3-j2+m1+k, d5=j3-j1-m2+k;
    if(d0<0||d1<0||d2<0||d3<0||d4<0||d5<0) continue;
    double denom = factd(d0)*factd(d1)*factd(d2)*factd(d3)*factd(d4)*factd(d5);
    s += ((k&1)?-1.0:1.0)/denom;
  }
  return pref*s;
}

static void make_q(int l, cd q[5][5]){
  for(int i=0;i<5;i++)for(int j=0;j<5;j++) q[i][j]=cd(0,0);
  double s = 1.0/std::sqrt(2.0);
  for(int m=-l;m<0;m++){
    q[l+m][l-m] = cd(s,0);
    q[l+m][l+m] = cd(0,-s);
  }
  q[l][l]=cd(1,0);
  for(int m=1;m<=l;m++){
    double sg = (m&1)?-1.0:1.0;
    q[l+m][l+m]=cd(sg*s,0);
    q[l+m][l-m]=cd(0,sg*s);
  }
  cd ph = (l==0)?cd(1,0) : ((l==1)?cd(0,-1) : cd(-1,0)); // (-i)^l
  for(int i=0;i<2*l+1;i++)for(int j=0;j<2*l+1;j++) q[i][j]*=ph;
}

static void real_cg(int l1,int l2,int l3, double* out){
  int d1=2*l1+1,d2=2*l2+1,d3=2*l3+1;
  double cg[125];
  for(int a=0;a<d1;a++)for(int b=0;b<d2;b++)for(int c=0;c<d3;c++)
    cg[(a*d2+b)*d3+c] = su2_cg(l1,l2,l3,a-l1,b-l2,c-l3);
  cd q1[5][5],q2[5][5],q3[5][5];
  make_q(l1,q1); make_q(l2,q2); make_q(l3,q3);
  cd C[125];
  for(int t=0;t<d1*d2*d3;t++) C[t]=cd(0,0);
  for(int i=0;i<d1;i++)for(int k=0;k<d2;k++)for(int n=0;n<d3;n++){
    double v = cg[(i*d2+k)*d3+n];
    if(v==0.0) continue;
    for(int j=0;j<d1;j++){
      cd a = q1[i][j]*v;
      if(a.real()==0.0 && a.imag()==0.0) continue;
      for(int l=0;l<d2;l++){
        cd b = a*q2[k][l];
        for(int m=0;m<d3;m++) C[(j*d2+l)*d3+m] += b*std::conj(q3[n][m]);
      }
    }
  }
  double sre=0,sim=0;
  for(int t=0;t<d1*d2*d3;t++){ sre+=std::fabs(C[t].real()); sim+=std::fabs(C[t].imag()); }
  bool use_re = (sre>=sim);
  double nrm=0;
  for(int t=0;t<d1*d2*d3;t++){ double x=use_re?C[t].real():C[t].imag(); nrm+=x*x; }
  nrm=std::sqrt(nrm);
  for(int t=0;t<d1*d2*d3;t++){ double x=use_re?C[t].real():C[t].imag(); out[t]=x/nrm; }
}

// Flat CG pack (sizes: 1,9,25,9,9,45,45,25,45,25,125), alpha folded in.
struct CGPack { float v[363]; };

// ---------------------------------------------------------------------------
// Device helpers
// ---------------------------------------------------------------------------
__device__ __forceinline__ float silu_f(float x){ return x/(1.f+expf(-x)); }
__host__ __device__ constexpr int LOFF(int l){ return l==0?0:(l==1?1:4); }

template<int DI,int DJ,int DK>
__device__ __forceinline__ void tp_add(const float* __restrict__ C, const float* xi,
                                       const float* sh, float wn, float* mk){
  float tmp[DK];
#pragma unroll
  for(int c=0;c<DK;c++) tmp[c]=0.f;
#pragma unroll
  for(int a=0;a<DI;a++){
#pragma unroll
    for(int b=0;b<DJ;b++){
      float p = xi[a]*sh[b];
#pragma unroll
      for(int c=0;c<DK;c++) tmp[c] = fmaf(C[(a*DJ+b)*DK+c], p, tmp[c]);
    }
  }
#pragma unroll
  for(int c=0;c<DK;c++) mk[c] = fmaf(wn, tmp[c], mk[c]);
}

// ---------------------------------------------------------------------------
// FAST PATH kernels (gather-based, no float atomics)
// ---------------------------------------------------------------------------

// Per-edge precompute: SH (9) and h1 (64) -> workspace.
__global__ __launch_bounds__(512,1) void emp_pre_kernel(
  const float* __restrict__ evec, const float* __restrict__ w0,
  const float* __restrict__ w1, float* __restrict__ h1s,
  float* __restrict__ shs, int E)
{
  __shared__ float s_h0[TE][64];
  __shared__ float s_sh[TE][9];
  const int t=threadIdx.x, u=t&63, es=t>>6;
  const int e = blockIdx.x*TE+es;
  const bool valid = (e<E);
  float dist=0.f;
  if(valid){
    float ex=evec[e*3+0], ey=evec[e*3+1], ez=evec[e*3+2];
    dist = sqrtf(ex*ex+ey*ey+ez*ez);
    if(u==0){
      float inv = 1.f/fmaxf(dist,1e-9f);
      float x=ex*inv, y=ey*inv, z=ez*inv;
      const float s3=1.7320508075688772f, s5=2.2360679774997896f;
      s_sh[es][0]=1.f;
      s_sh[es][1]=s3*y; s_sh[es][2]=s3*z; s_sh[es][3]=s3*x;
      s_sh[es][4]=s5*s3*x*y; s_sh[es][5]=s5*s3*y*z; s_sh[es][6]=s5*(1.5f*z*z-0.5f);
      s_sh[es][7]=s5*s3*x*z; s_sh[es][8]=s5*0.5f*s3*(x*x-y*y);
    }
  }
  s_h0[es][u] = silu_f(dist * w0[u]);
  __syncthreads();
  if(valid && u<9) shs[(size_t)e*12+u] = s_sh[es][u];
  float acc = 0.f;
#pragma unroll
  for(int k=0;k<64;k++) acc = fmaf(s_h0[es][k], w1[k*64+u], acc);
  if(valid) h1s[(size_t)e*64+u] = silu_f(acc*0.125f);
}

// CSR build: histogram over dst
__global__ void hist_kernel(const int* __restrict__ dst, int* __restrict__ cnt, int E){
  int i = blockIdx.x*blockDim.x + threadIdx.x;
  if(i<E) atomicAdd(&cnt[dst[i]], 1);
}

// Exclusive scan over N counts (single block, 1024 threads)
__global__ __launch_bounds__(1024) void scan_kernel(const int* __restrict__ cnt,
                                                    int* __restrict__ row_ptr, int N){
  __shared__ int s_part[1024];
  const int t = threadIdx.x;
  const int per = (N + 1023) >> 10;
  const int b0 = t*per, b1 = min(N, b0+per);
  int local = 0;
  for(int i=b0;i<b1;i++) local += cnt[i];
  s_part[t] = local;
  __syncthreads();
  for(int off=1; off<1024; off<<=1){
    int v = (t>=off) ? s_part[t-off] : 0;
    __syncthreads();
    s_part[t] += v;
    __syncthreads();
  }
  int run = (t==0) ? 0 : s_part[t-1];
  for(int i=b0;i<b1;i++){ row_ptr[i] = run; run += cnt[i]; }
  if(t==1023) row_ptr[N] = s_part[1023];
}

// Fill buckets (order within bucket nondeterministic here; canonicalized below)
__global__ void fill_kernel(const int* __restrict__ dst, const int* __restrict__ row_ptr,
                            int* __restrict__ cnt2, int* __restrict__ sorted, int E){
  int i = blockIdx.x*blockDim.x + threadIdx.x;
  if(i<E){
    int d = dst[i];
    int pos = atomicAdd(&cnt2[d], 1);
    sorted[row_ptr[d]+pos] = i;
  }
}

// Canonicalize: per-node insertion sort of its edge-id slice (deg ~ 10)
__global__ void sortb_kernel(int* __restrict__ sorted, const int* __restrict__ row_ptr, int N){
  int n = blockIdx.x*blockDim.x + threadIdx.x;
  if(n>=N) return;
  int b=row_ptr[n], e=row_ptr[n+1];
  for(int i=b+1;i<e;i++){
    int v=sorted[i]; int j=i-1;
    while(j>=b && sorted[j]>v){ sorted[j+1]=sorted[j]; j--; }
    sorted[j+1]=v;
  }
}

// Gather-aggregate: one block (4 waves) per node; TP in registers; no atomics.
__global__ __launch_bounds__(256,2) void emp_gather_kernel(
  const float* __restrict__ nf, const float* __restrict__ h1s,
  const float* __restrict__ shs, const int* __restrict__ sorted,
  const int* __restrict__ row_ptr, const int* __restrict__ src_idx,
  const float* __restrict__ w2, float* __restrict__ aggr, CGPack cgp)
{
  __shared__ float s_tile[64][64];  // 16 KB  fc_w2 instruction tile
  __shared__ float s_x[8][576];     // 18 KB  nf[src] rows for chunk
  __shared__ float s_h1[8][64];     //  2 KB
  __shared__ float s_sh[8][12];
  __shared__ int   s_eid[8];
  __shared__ int   s_src[8];
  __shared__ float s_red[4][576];   //  9 KB  cross-wave reduction

  const int n = blockIdx.x;
  const int t = threadIdx.x;
  const int u = t & 63;
  const int w = t >> 6;
  const int beg = row_ptr[n], end = row_ptr[n+1];

  float mg[9];
#pragma unroll
  for(int i=0;i<9;i++) mg[i]=0.f;

  for(int base=beg; base<end; base+=8){
    const int C = min(8, end-base);
    if(t < C){ int e = sorted[base+t]; s_eid[t]=e; s_src[t]=src_idx[e]; }
    __syncthreads();
    for(int idx=t; idx<C*576; idx+=256){
      int c = idx/576, j = idx - 576*c;
      s_x[c][j] = nf[(size_t)s_src[c]*NODE_DIM + j];
    }
    for(int idx=t; idx<C*64; idx+=256){
      int c = idx>>6, j = idx&63;
      s_h1[c][j] = h1s[(size_t)s_eid[c]*64 + j];
    }
    if(t < C*12){
      int c = t/12, j = t - 12*c;
      if(j<9) s_sh[c][j] = shs[(size_t)s_eid[c]*12 + j];
    }
    __syncthreads();

#define GI(N_, LI, LJ, LK, OFF)                                              \
    {                                                                        \
      for(int idx=t; idx<4096; idx+=256){                                    \
        int k = idx>>6, j = idx&63;                                          \
        s_tile[k][j] = w2[k*704 + (N_)*64 + j];                              \
      }                                                                      \
      __syncthreads();                                                       \
      for(int c=w; c<C; c+=4){                                               \
        float wn = 0.f;                                                      \
        _Pragma("unroll")                                                    \
        for(int k=0;k<64;k++) wn = fmaf(s_h1[c][k], s_tile[k][u], wn);       \
        wn *= 0.125f;                                                        \
        const int xb = (LI)==0 ? u : ((LI)==1 ? 64+u*3 : 256+u*5);           \
        tp_add<2*(LI)+1,2*(LJ)+1,2*(LK)+1>(cgp.v+(OFF), &s_x[c][xb],         \
                                           &s_sh[c][LOFF(LJ)], wn,           \
                                           mg+LOFF(LK));                     \
      }                                                                      \
      __syncthreads();                                                       \
    }

    GI(0,0,0,0,0)
    GI(1,0,1,1,1)
    GI(2,0,2,2,10)
    GI(3,1,0,1,35)
    GI(4,1,1,0,44)
    GI(5,1,1,2,53)
    GI(6,1,2,1,98)
    GI(7,2,0,2,143)
    GI(8,2,1,1,168)
    GI(9,2,2,0,213)
    GI(10,2,2,2,238)
#undef GI
  }

  // cross-wave reduce and coalesced store of this node's aggr row
  s_red[w][u] = mg[0];
#pragma unroll
  for(int a=0;a<3;a++) s_red[w][64+u*3+a] = mg[1+a];
#pragma unroll
  for(int a=0;a<5;a++) s_red[w][256+u*5+a] = mg[4+a];
  __syncthreads();
  float* arow = aggr + (size_t)n*NODE_DIM;
  for(int idx=t; idx<NODE_DIM; idx+=256)
    arow[idx] = s_red[0][idx]+s_red[1][idx]+s_red[2][idx]+s_red[3][idx];
}

// ---------------------------------------------------------------------------
// FALLBACK PATH (verified round-4 atomic kernel) — used only if ws too small
// ---------------------------------------------------------------------------
__global__ __launch_bounds__(512,1) void emp_edge_kernel(
  const float* __restrict__ nf, const int* __restrict__ src_idx, const int* __restrict__ dst_idx,
  const float* __restrict__ evec, const float* __restrict__ w0, const float* __restrict__ w1,
  const float* __restrict__ w2, float* __restrict__ aggr, int E, CGPack cgp)
{
  __shared__ float s_h0[TE][64];
  __shared__ float s_h1[TE][64];
  __shared__ float s_sh[TE][9];
  __shared__ int   s_sd[TE][2];
  __shared__ float s_tile[64][64];

  const int t  = threadIdx.x;
  const int u  = t & 63;
  const int es = t >> 6;
  const int e  = blockIdx.x*TE + es;
  const bool valid = (e < E);

  float dist = 0.f;
  if(valid){
    float ex = evec[e*3+0], ey = evec[e*3+1], ez = evec[e*3+2];
    dist = sqrtf(ex*ex+ey*ey+ez*ez);
    if(u==0){
      float inv = 1.f/fmaxf(dist,1e-9f);
      float x=ex*inv, y=ey*inv, z=ez*inv;
      const float s3=1.7320508075688772f, s5=2.2360679774997896f;
      s_sh[es][0]=1.f;
      s_sh[es][1]=s3*y; s_sh[es][2]=s3*z; s_sh[es][3]=s3*x;
      s_sh[es][4]=s5*s3*x*y; s_sh[es][5]=s5*s3*y*z; s_sh[es][6]=s5*(1.5f*z*z-0.5f);
      s_sh[es][7]=s5*s3*x*z; s_sh[es][8]=s5*0.5f*s3*(x*x-y*y);
      s_sd[es][0]=src_idx[e]; s_sd[es][1]=dst_idx[e];
    }
  }
  s_h0[es][u] = silu_f(dist * w0[u]);
  __syncthreads();

  float acc = 0.f;
#pragma unroll
  for(int k=0;k<64;k++) acc = fmaf(s_h0[es][k], w1[k*64+u], acc);
  s_h1[es][u] = silu_f(acc*0.125f);

  float xa[9], shv[9], mg[9];
#pragma unroll
  for(int i=0;i<9;i++) mg[i]=0.f;
  int srcn=0, dstn=0;
  if(valid){ srcn = s_sd[es][0]; dstn = s_sd[es][1]; }
#pragma unroll
  for(int i=0;i<9;i++) shv[i] = valid ? s_sh[es][i] : 0.f;
  if(valid){
    const float* row = nf + (size_t)srcn*NODE_DIM;
    xa[0] = row[u];
#pragma unroll
    for(int a=0;a<3;a++) xa[1+a]=row[64+u*3+a];
#pragma unroll
    for(int a=0;a<5;a++) xa[4+a]=row[256+u*5+a];
  } else {
#pragma unroll
    for(int i=0;i<9;i++) xa[i]=0.f;
  }

#define TP_INST(N, LI, LJ, LK, OFF)                                         \
  {                                                                          \
    __syncthreads();                                                         \
    _Pragma("unroll")                                                        \
    for(int r=0;r<8;r++){ int k=es+r*8; s_tile[k][u] = w2[k*704 + (N)*64 + u]; } \
    __syncthreads();                                                         \
    float wn=0.f;                                                            \
    _Pragma("unroll")                                                        \
    for(int k=0;k<64;k++) wn = fmaf(s_h1[es][k], s_tile[k][u], wn);          \
    wn *= 0.125f;                                                            \
    tp_add<2*(LI)+1,2*(LJ)+1,2*(LK)+1>(cgp.v+(OFF), xa+LOFF(LI),             \
                                       shv+LOFF(LJ), wn, mg+LOFF(LK));       \
  }
  TP_INST(0,0,0,0,0)
  TP_INST(1,0,1,1,1)
  TP_INST(2,0,2,2,10)
  TP_INST(3,1,0,1,35)
  TP_INST(4,1,1,0,44)
  TP_INST(5,1,1,2,53)
  TP_INST(6,1,2,1,98)
  TP_INST(7,2,0,2,143)
  TP_INST(8,2,1,1,168)
  TP_INST(9,2,2,0,213)
  TP_INST(10,2,2,2,238)
#undef TP_INST

  if(valid){
    float* arow = aggr + (size_t)dstn*NODE_DIM;
    atomicAdd(&arow[u], mg[0]);
#pragma unroll
    for(int c=0;c<3;c++) atomicAdd(&arow[64+u*3+c], mg[1+c]);
#pragma unroll
    for(int c=0;c<5;c++) atomicAdd(&arow[256+u*5+c], mg[4+c]);
  }
}

// Per-node: out_row = blockdiag-linear(aggr_row)/8 + node_feat_row, in place.
__global__ __launch_bounds__(64) void emp_node_kernel(
  const float* __restrict__ nf, const float* __restrict__ lw,
  float* __restrict__ out, int N)
{
  __shared__ float s_a[NODE_DIM];
  const int n = blockIdx.x;
  const int v = threadIdx.x;
  float* orow = out + (size_t)n*NODE_DIM;
#pragma unroll
  for(int r=0;r<9;r++) s_a[r*64+v] = orow[r*64+v];
  __syncthreads();

  float o0=0.f, o1[3]={0.f,0.f,0.f}, o2[5]={0.f,0.f,0.f,0.f,0.f};
#pragma unroll 8
  for(int uu=0;uu<64;uu++){
    float wv0 = lw[uu*64+v];
    o0 = fmaf(s_a[uu], wv0, o0);
    float wv1 = lw[4096+uu*64+v];
#pragma unroll
    for(int d=0;d<3;d++) o1[d]=fmaf(s_a[64+uu*3+d],wv1,o1[d]);
    float wv2 = lw[8192+uu*64+v];
#pragma unroll
    for(int d=0;d<5;d++) o2[d]=fmaf(s_a[256+uu*5+d],wv2,o2[d]);
  }
  const float* nrow = nf + (size_t)n*NODE_DIM;
  orow[v] = fmaf(o0,0.125f,nrow[v]);
#pragma unroll
  for(int d=0;d<3;d++) orow[64+v*3+d]=fmaf(o1[d],0.125f,nrow[64+v*3+d]);
#pragma unroll
  for(int d=0;d<5;d++) orow[256+v*5+d]=fmaf(o2[d],0.125f,nrow[256+v*5+d]);
}

// ---------------------------------------------------------------------------
extern "C" void kernel_launch(void* const* d_in, const int* in_sizes, int n_in,
                              void* d_out, int out_size, void* d_ws, size_t ws_size,
                              hipStream_t stream)
{
  const float* nf   = (const float*)d_in[0];
  const int*   eidx = (const int*)  d_in[1];
  const float* evec = (const float*)d_in[2];
  const float* w0   = (const float*)d_in[3];
  const float* w1   = (const float*)d_in[4];
  const float* w2   = (const float*)d_in[5];
  const float* lw   = (const float*)d_in[6];
  const int E = in_sizes[1]/2;
  const int N = in_sizes[0]/NODE_DIM;
  const int* src = eidx;
  const int* dst = eidx + E;

  // Build CG pack (alpha folded in).
  CGPack cgp;
  {
    const int II[11]={0,0,0,1,1,1,1,2,2,2,2};
    const int JJ[11]={0,1,2,0,1,1,2,0,1,2,2};
    const int KK[11]={0,1,2,1,0,2,1,2,1,0,2};
    const int OFF[11]={0,1,10,35,44,53,98,143,168,213,238};
    const double npaths[3]={3.0,4.0,4.0};
    double tmp[125];
    for(int n=0;n<11;n++){
      int li=II[n], lj=JJ[n], lk=KK[n];
      real_cg(li,lj,lk,tmp);
      double alpha = std::sqrt((2.0*lk+1.0)/npaths[lk]);
      int sz=(2*li+1)*(2*lj+1)*(2*lk+1);
      for(int q=0;q<sz;q++) cgp.v[OFF[n]+q]=(float)(tmp[q]*alpha);
    }
  }

  // Workspace layout (256B aligned): h1s | shs | sorted | cnt | cnt2 | row_ptr
  auto align256 = [](size_t x){ return (x + 255) & ~(size_t)255; };
  size_t off = 0;
  size_t o_h1  = off; off = align256(off + (size_t)E*64*sizeof(float));
  size_t o_sh  = off; off = align256(off + (size_t)E*12*sizeof(float));
  size_t o_srt = off; off = align256(off + (size_t)E*sizeof(int));
  size_t o_cnt = off; off = align256(off + (size_t)N*2*sizeof(int)); // cnt + cnt2 contiguous
  size_t o_rp  = off; off = align256(off + (size_t)(N+1)*sizeof(int));
  const size_t need = off;

  if(ws_size >= need){
    // ---------------- FAST PATH: gather-based, no float atomics ----------
    char* ws = (char*)d_ws;
    float* h1s    = (float*)(ws + o_h1);
    float* shs    = (float*)(ws + o_sh);
    int*   sorted = (int*)  (ws + o_srt);
    int*   cnt    = (int*)  (ws + o_cnt);
    int*   cnt2   = cnt + N;
    int*   row_ptr= (int*)  (ws + o_rp);

    hipMemsetAsync(cnt, 0, (size_t)N*2*sizeof(int), stream);

    hipLaunchKernelGGL(emp_pre_kernel, dim3((E+TE-1)/TE), dim3(512), 0, stream,
                       evec, w0, w1, h1s, shs, E);
    hipLaunchKernelGGL(hist_kernel, dim3((E+255)/256), dim3(256), 0, stream,
                       dst, cnt, E);
    hipLaunchKernelGGL(scan_kernel, dim3(1), dim3(1024), 0, stream,
                       cnt, row_ptr, N);
    hipLaunchKernelGGL(fill_kernel, dim3((E+255)/256), dim3(256), 0, stream,
                       dst, row_ptr, cnt2, sorted, E);
    hipLaunchKernelGGL(sortb_kernel, dim3((N+255)/256), dim3(256), 0, stream,
                       sorted, row_ptr, N);
    hipLaunchKernelGGL(emp_gather_kernel, dim3(N), dim3(256), 0, stream,
                       nf, h1s, shs, sorted, row_ptr, src, w2, (float*)d_out, cgp);
    hipLaunchKernelGGL(emp_node_kernel, dim3(N), dim3(64), 0, stream,
                       nf, lw, (float*)d_out, N);
  } else {
    // ---------------- FALLBACK: verified atomic path ---------------------
    hipMemsetAsync(d_out, 0, (size_t)N*NODE_DIM*sizeof(float), stream);
    hipLaunchKernelGGL(emp_edge_kernel, dim3((E+TE-1)/TE), dim3(512), 0, stream,
                       nf, src, dst, evec, w0, w1, w2, (float*)d_out, E, cgp);
    hipLaunchKernelGGL(emp_node_kernel, dim3(N), dim3(64), 0, stream,
                       nf, lw, (float*)d_out, N);
  }
}